// Round 1
// baseline (378.032 us; speedup 1.0000x reference)
//
#include <hip/hip_runtime.h>
#include <hip/hip_bf16.h>
#include <cstddef>

// Problem constants
#define BSZ 8
#define T_  8
#define L_  196
#define D_  192
#define E_  192
#define C_  1536   // E*T
#define N_  16
#define K_  4
#define R_  96

// ---------------- Kernel 1: in_proj GEMM ----------------
// xz[b,e,t,l] = sum_d hidden[b,t,l,d] * W[e,d]
// rows m = (b*T + t)*L + l  (M = 12544), cols e (N = 384), K = 192
// write x (e<192) / z (e>=192) at [(b*1536 + e'*8 + t)*196 + l]
#define BM 64
#define BN 64
#define BKK 32
__global__ __launch_bounds__(256) void k_inproj(
    const float* __restrict__ A,   // hidden, M x 192
    const float* __restrict__ W,   // 384 x 192
    float* __restrict__ xb, float* __restrict__ zb) {
  __shared__ float As[BKK][BM + 4];
  __shared__ float Bs[BKK][BN + 4];
  int tid = threadIdx.x;
  int m0 = blockIdx.x * BM;
  int n0 = blockIdx.y * BN;
  int tx = tid & 15, ty = tid >> 4;
  float acc[4][4] = {};
  for (int k0 = 0; k0 < 192; k0 += BKK) {
#pragma unroll
    for (int i = 0; i < 8; i++) {
      int idx = tid + i * 256;
      int m = idx >> 5, k = idx & 31;
      As[k][m] = A[(size_t)(m0 + m) * 192 + k0 + k];
    }
#pragma unroll
    for (int i = 0; i < 8; i++) {
      int idx = tid + i * 256;
      int n = idx >> 5, k = idx & 31;
      Bs[k][n] = W[(size_t)(n0 + n) * 192 + k0 + k];
    }
    __syncthreads();
#pragma unroll
    for (int kk = 0; kk < BKK; kk++) {
      float a[4], bb[4];
#pragma unroll
      for (int i = 0; i < 4; i++) a[i] = As[kk][ty * 4 + i];
#pragma unroll
      for (int j = 0; j < 4; j++) bb[j] = Bs[kk][tx * 4 + j];
#pragma unroll
      for (int i = 0; i < 4; i++)
#pragma unroll
        for (int j = 0; j < 4; j++) acc[i][j] += a[i] * bb[j];
    }
    __syncthreads();
  }
#pragma unroll
  for (int i = 0; i < 4; i++) {
    int m = m0 + ty * 4 + i;
    int b = m / (T_ * L_);
    int r = m % (T_ * L_);
    int t = r / L_;
    int l = r % L_;
#pragma unroll
    for (int j = 0; j < 4; j++) {
      int e = n0 + tx * 4 + j;
      float v = acc[i][j];
      if (e < E_) {
        int c = e * T_ + t;
        xb[((size_t)b * C_ + c) * L_ + l] = v;
      } else {
        int c = (e - E_) * T_ + t;
        zb[((size_t)b * C_ + c) * L_ + l] = v;
      }
    }
  }
}

// ---------------- Kernel 2: depthwise causal conv (K=4) + bias + SiLU ----------------
__global__ __launch_bounds__(256) void k_conv(
    const float* __restrict__ xb, const float* __restrict__ conv_w,
    const float* __restrict__ conv_b, float* __restrict__ xc) {
  int idx = blockIdx.x * 256 + threadIdx.x;   // B*C*L = 2408448 exactly
  int l = idx % L_;
  int bc = idx / L_;
  int c = bc % C_;
  const float* xrow = xb + (size_t)bc * L_;
  const float* w = conv_w + c * K_;
  float acc = conv_b[c];
#pragma unroll
  for (int k = 0; k < K_; k++) {
    int ll = l - (K_ - 1) + k;
    if (ll >= 0) acc += xrow[ll] * w[k];
  }
  xc[idx] = acc / (1.f + expf(-acc));
}

// ---------------- Kernel 3: x_dbl GEMM ----------------
// xdbl[b,r,l] = sum_c W[r,c] * xc[b,c,l]  (128 x 1536 x 196 per batch)
// each thread computes rows r0 and r0+64 for one l
__global__ __launch_bounds__(256) void k_xdbl(
    const float* __restrict__ xc, const float* __restrict__ W,  // 128 x 1536
    float* __restrict__ xdbl) {
  int tx = threadIdx.x & 63;
  int ty = threadIdx.x >> 6;
  int l = blockIdx.x * 64 + tx;
  int r0 = blockIdx.y * 4 + ty;
  int r1 = r0 + 64;
  int b = blockIdx.z;
  if (l >= L_) return;
  const float* xcb = xc + (size_t)b * C_ * L_;
  float acc0 = 0.f, acc1 = 0.f;
#pragma unroll 4
  for (int c = 0; c < C_; c++) {
    float v = xcb[(size_t)c * L_ + l];
    acc0 += v * W[(size_t)r0 * C_ + c];
    acc1 += v * W[(size_t)r1 * C_ + c];
  }
  xdbl[((size_t)b * 128 + r0) * L_ + l] = acc0;
  xdbl[((size_t)b * 128 + r1) * L_ + l] = acc1;
}

// ---------------- Kernel 4: delta GEMM + softplus ----------------
// delta[b,c,l] = softplus(sum_r xdbl[b,r,l]*Wdt[c,r] + dt_bias[c])
__global__ __launch_bounds__(256) void k_delta(
    const float* __restrict__ xdbl, const float* __restrict__ Wdt,  // 1536 x 96
    const float* __restrict__ dt_bias, float* __restrict__ delta) {
  int tx = threadIdx.x & 63;
  int ty = threadIdx.x >> 6;
  int l = blockIdx.x * 64 + tx;
  int c = blockIdx.y * 4 + ty;
  int b = blockIdx.z;
  if (l >= L_) return;
  const float* dt = xdbl + (size_t)b * 128 * L_;  // rows 0..95 are dt
  float acc = 0.f;
#pragma unroll 8
  for (int r = 0; r < R_; r++)
    acc += dt[(size_t)r * L_ + l] * Wdt[(size_t)c * R_ + r];
  acc += dt_bias[c];
  float sp = (acc > 20.f) ? acc : log1pf(expf(acc));
  delta[((size_t)b * C_ + c) * L_ + l] = sp;
}

// ---------------- Kernel 5: selective scan + output fuse ----------------
// lane = (b,c,n); 16 lanes per (b,c); shuffle-reduce y over n; lane0 writes out
__global__ __launch_bounds__(256) void k_scan(
    const float* __restrict__ delta, const float* __restrict__ xc,
    const float* __restrict__ zb, const float* __restrict__ xdbl,
    const float* __restrict__ A_log, const float* __restrict__ D_param,
    float* __restrict__ out) {
  int idx = blockIdx.x * 256 + threadIdx.x;   // B*C*16 = 196608 exactly
  int n = idx & 15;
  int pair = idx >> 4;
  int b = pair / C_;
  int c = pair % C_;
  float a = -expf(A_log[c * N_ + n]);
  float Dp = D_param[c];
  const float* dp = delta + ((size_t)b * C_ + c) * L_;
  const float* xp = xc + ((size_t)b * C_ + c) * L_;
  const float* zp = zb + ((size_t)b * C_ + c) * L_;
  const float* Bp = xdbl + ((size_t)b * 128 + R_ + n) * L_;
  const float* Cp = xdbl + ((size_t)b * 128 + R_ + N_ + n) * L_;
  float* op = out + ((size_t)b * C_ + c) * L_;
  float h = 0.f;
  for (int l = 0; l < L_; l++) {
    float d = dp[l];
    float xv = xp[l];
    float dA = expf(d * a);
    h = h * dA + d * xv * Bp[l];
    float yv = h * Cp[l];
    yv += __shfl_xor(yv, 1);
    yv += __shfl_xor(yv, 2);
    yv += __shfl_xor(yv, 4);
    yv += __shfl_xor(yv, 8);
    if (n == 0) {
      float zv = zp[l];
      float sz = zv / (1.f + expf(-zv));
      op[l] = (yv + xv * Dp) * sz;
    }
  }
}

extern "C" void kernel_launch(void* const* d_in, const int* in_sizes, int n_in,
                              void* d_out, int out_size, void* d_ws, size_t ws_size,
                              hipStream_t stream) {
  const float* hidden    = (const float*)d_in[0];
  const float* in_proj_w = (const float*)d_in[1];
  const float* conv_w    = (const float*)d_in[2];
  const float* conv_b    = (const float*)d_in[3];
  const float* x_proj_w  = (const float*)d_in[4];
  const float* dt_proj_w = (const float*)d_in[5];
  const float* dt_bias   = (const float*)d_in[6];
  const float* A_log     = (const float*)d_in[7];
  const float* D_param   = (const float*)d_in[8];
  float* out = (float*)d_out;

  const size_t NBCL = (size_t)BSZ * C_ * L_;   // 2408448
  float* ws = (float*)d_ws;
  float* xb   = ws;                 // pre-conv x  (reused as delta later)
  float* zb   = xb + NBCL;
  float* xc   = zb + NBCL;          // post-conv x
  float* xdbl = xc + NBCL;          // B*128*L = 200704
  float* delta = xb;                // reuse: xb dead after conv

  // K1: in_proj GEMM  (M=12544 = 196*64, N=384 = 6*64)
  k_inproj<<<dim3(196, 6), 256, 0, stream>>>(hidden, in_proj_w, xb, zb);
  // K2: conv + silu
  k_conv<<<(int)(NBCL / 256), 256, 0, stream>>>(xb, conv_w, conv_b, xc);
  // K3: x_dbl GEMM
  k_xdbl<<<dim3(4, 16, BSZ), 256, 0, stream>>>(xc, x_proj_w, xdbl);
  // K4: delta GEMM + softplus
  k_delta<<<dim3(4, C_ / 4, BSZ), 256, 0, stream>>>(xdbl, dt_proj_w, dt_bias, delta);
  // K5: scan + output
  k_scan<<<(BSZ * C_ * N_) / 256, 256, 0, stream>>>(delta, xc, zb, xdbl, A_log, D_param, out);
}